// Round 11
// baseline (2123.964 us; speedup 1.0000x reference)
//
#include <hip/hip_runtime.h>
#include <hip/hip_bf16.h>

#define IDIM 80
#define HDIM 512
#define ODIM 128
#define G5   5
#define BB   512
#define TT   512
#define PDIM 1285          // G*2*ODIM + G
#define GDIM 1536          // 3*HDIM
#define NB   16            // persistent blocks (producers)
#define TPB  768           // threads per block (12 waves)
#define EPB  32            // h-elements per block
#define ROWS 96            // gh rows per block (3*EPB)
#define PCPB 81            // proj cols per block (16*81=1296 >= 1285)

__device__ __forceinline__ void ag_storeu(unsigned long long* p, unsigned long long v) {
  __hip_atomic_store(p, v, __ATOMIC_RELAXED, __HIP_MEMORY_SCOPE_AGENT);
}
__device__ __forceinline__ unsigned long long ag_loadu(const unsigned long long* p) {
  return __hip_atomic_load(p, __ATOMIC_RELAXED, __HIP_MEMORY_SCOPE_AGENT);
}
__device__ __forceinline__ int PHYS(int j) { return (j >> 5) * 36 + (j & 31); }

// 16 blocks. Block nb owns h[nb*32 .. nb*32+32).
// Per step: 96 gh dots in parallel (8 thr/row, K=64, shfl-reduce) -> LDS;
// 32 gate threads fuse gates and publish ONE tagged 8B word per element
// (AGENT store, proven). Consumers poll ONE word each (single AGENT load per
// iteration — no chained round trips), self-owned words skipped.
// xp is block-private (plain cached slab, r9-proven) -> no grid barrier.
// Proj GEMM fused, VGPR-resident weights (r8-proven), in the visibility window.
// WAR on hOut parity buffer safe by induction: tag-b store implies all
// consumed b-1, whose stores implied all consumed b-2 (the slot overwritten).
__global__ void __launch_bounds__(TPB) gru_kernel(
    const float* __restrict__ ys, const float* __restrict__ W_ih,
    const float* __restrict__ W_hh, const float* __restrict__ b_ih,
    const float* __restrict__ b_hh, const float* __restrict__ W_proj,
    const float* __restrict__ b_proj,
    unsigned long long* __restrict__ hOut, float* __restrict__ xp_loc,
    float* __restrict__ params)
{
  const int tid = threadIdx.x;
  const int nb  = blockIdx.x;
  const int s   = tid & 7;           // 0..7  K-octant (64 cols)
  const int row = tid >> 3;          // 0..95 local gh row / proj col

  __shared__ float wih[ROWS * 82];   // phase-0 W_ih rows (31.5 KB)
  __shared__ float bihs[ROWS];
  __shared__ float hs[2][16 * 36];   // h double buffer, padded stride 36
  __shared__ float dots[ROWS];       // per-step gh dots

  // --- W_hh slice -> registers: row gr, cols [s*64, s*64+64) = 16 float4 ---
  const int gr = (row >> 5) * HDIM + nb * EPB + (row & 31);
  float4 wreg[16];
  {
    const float4* wrow = (const float4*)(W_hh + (size_t)gr * HDIM + s * 64);
    #pragma unroll
    for (int i = 0; i < 16; ++i) wreg[i] = wrow[i];
  }
  const float brow = b_hh[gr];

  // --- W_proj slice -> registers: col nb*81+row, same K-octant split ---
  const int pcol = nb * PCPB + row;
  const bool pact = (row < PCPB) && (pcol < PDIM);
  float4 wpreg[16] = {};
  float bp = 0.f;
  if (pact) {
    const float4* wrow = (const float4*)(W_proj + (size_t)pcol * HDIM + s * 64);
    #pragma unroll
    for (int i = 0; i < 16; ++i) wpreg[i] = wrow[i];
    bp = b_proj[pcol];
  }

  for (int w = tid; w < 2 * 16 * 36; w += TPB) ((float*)hs)[w] = 0.f;

  // --- phase 0: block-private xp slab (96 rows x 512 steps), plain stores ---
  for (int idx = tid; idx < ROWS * IDIM; idx += TPB) {
    int L = idx / IDIM, f = idx - L * IDIM;
    int grr = (L >> 5) * HDIM + nb * EPB + (L & 31);
    wih[L * 82 + f] = W_ih[(size_t)grr * IDIM + f];
  }
  if (tid < ROWS) {
    int grr = (tid >> 5) * HDIM + nb * EPB + (tid & 31);
    bihs[tid] = b_ih[grr];
  }
  __syncthreads();
  {
    const int L = tid % ROWS, b8 = tid / ROWS;   // 768 = 8*96 exactly
    float* xq = xp_loc + (size_t)nb * BB * ROWS;
    for (int pass = 0; pass < 64; ++pass) {
      int b = pass * 8 + b8;
      const float* yrow = ys + ((size_t)b * TT + TT - 1) * IDIM;
      float acc = bihs[L];
      #pragma unroll
      for (int f = 0; f < IDIM; f += 2) {
        float2 wv = *(const float2*)&wih[L * 82 + f];
        float2 yv = *(const float2*)&yrow[f];
        acc += wv.x * yv.x + wv.y * yv.y;
      }
      xq[(size_t)b * ROWS + L] = acc;            // plain: same-CU prod/consumer
    }
  }
  __syncthreads();

  const float* xq = xp_loc + (size_t)nb * BB * ROWS;

  for (int b = 0; b < BB; ++b) {
    const int cur = b & 1, nxt = cur ^ 1;

    // gate-thread xp for this step, issued early (plain cached loads)
    float xr = 0.f, xz = 0.f, xn = 0.f;
    if (tid < EPB) {
      const float* xb = xq + (size_t)b * ROWS;
      xr = xb[tid]; xz = xb[32 + tid]; xn = xb[64 + tid];
    }

    // ---- 96 dots in parallel: thread (row,s) covers cols [s*64, s*64+64) ----
    {
      const float* h0 = &hs[cur][(2 * s) * 36];
      const float* h1 = &hs[cur][(2 * s + 1) * 36];
      float a0 = 0.f, a1 = 0.f, a2 = 0.f, a3 = 0.f;
      #pragma unroll
      for (int m = 0; m < 8; ++m) {
        float4 h4 = ((const float4*)h0)[m]; float4 w4 = wreg[m];
        a0 += w4.x * h4.x; a1 += w4.y * h4.y;
        a2 += w4.z * h4.z; a3 += w4.w * h4.w;
      }
      #pragma unroll
      for (int m = 0; m < 8; ++m) {
        float4 h4 = ((const float4*)h1)[m]; float4 w4 = wreg[8 + m];
        a0 += w4.x * h4.x; a1 += w4.y * h4.y;
        a2 += w4.z * h4.z; a3 += w4.w * h4.w;
      }
      float dot = (a0 + a1) + (a2 + a3);
      dot += __shfl_xor(dot, 1);
      dot += __shfl_xor(dot, 2);
      dot += __shfl_xor(dot, 4);
      if (s == 0) dots[row] = dot + brow;
    }
    __syncthreads();                             // dots ready

    // ---- gates + ONE-word exchange store (32 gate threads) ----
    if (tid < EPB) {
      float hr = dots[tid], hz = dots[32 + tid], hn = dots[64 + tid];
      int jo = nb * EPB + tid;
      float h_old = hs[cur][PHYS(jo)];
      float r = 1.f / (1.f + __expf(-(xr + hr)));
      float z = 1.f / (1.f + __expf(-(xz + hz)));
      float e2 = __expf(2.f * (xn + r * hn));
      float n = 1.f - 2.f / (e2 + 1.f);          // tanh, overflow-safe
      float hnew = (1.f - z) * n + z * h_old;
      hs[nxt][PHYS(jo)] = hnew;                  // own element: direct
      union { float f; unsigned u; } cv; cv.f = hnew;
      ag_storeu(&hOut[(size_t)cur * HDIM + jo],
                ((unsigned long long)(unsigned)b << 32) | cv.u);
    }

    // ---- proj of row b-1 in the visibility window (VGPR weights) ----
    if (b >= 1 && pact) {
      const float* h0 = &hs[cur][(2 * s) * 36];
      const float* h1 = &hs[cur][(2 * s + 1) * 36];
      float p0 = 0.f, p1 = 0.f, p2 = 0.f, p3 = 0.f;
      #pragma unroll
      for (int m = 0; m < 8; ++m) {
        float4 h4 = ((const float4*)h0)[m]; float4 w4 = wpreg[m];
        p0 += w4.x * h4.x; p1 += w4.y * h4.y;
        p2 += w4.z * h4.z; p3 += w4.w * h4.w;
      }
      #pragma unroll
      for (int m = 0; m < 8; ++m) {
        float4 h4 = ((const float4*)h1)[m]; float4 w4 = wpreg[8 + m];
        p0 += w4.x * h4.x; p1 += w4.y * h4.y;
        p2 += w4.z * h4.z; p3 += w4.w * h4.w;
      }
      float pr = (p0 + p1) + (p2 + p3);
      pr += __shfl_xor(pr, 1);
      pr += __shfl_xor(pr, 2);
      pr += __shfl_xor(pr, 4);
      if (s == 0) params[(size_t)(b - 1) * PDIM + pcol] = pr + bp;
    }

    // ---- poll ONE word (single AGENT load per iteration) ----
    if (tid < HDIM) {
      const bool own = (tid >= nb * EPB) && (tid < nb * EPB + EPB);
      if (!own) {
        const unsigned long long* src = &hOut[(size_t)cur * HDIM + tid];
        unsigned long long v; int guard = 0;
        do {
          v = ag_loadu(src);
        } while ((unsigned)(v >> 32) != (unsigned)b && ++guard < (1 << 20));
        union { unsigned u; float f; } hv; hv.u = (unsigned)v;
        hs[nxt][PHYS(tid)] = hv.f;
      }
    }
    __syncthreads();                             // h_b complete
  }

  // epilogue: proj row 511 from hs[0] (= h after step 511)
  if (pact) {
    const float* h0 = &hs[0][(2 * s) * 36];
    const float* h1 = &hs[0][(2 * s + 1) * 36];
    float p0 = 0.f, p1 = 0.f, p2 = 0.f, p3 = 0.f;
    #pragma unroll
    for (int m = 0; m < 8; ++m) {
      float4 h4 = ((const float4*)h0)[m]; float4 w4 = wpreg[m];
      p0 += w4.x * h4.x; p1 += w4.y * h4.y;
      p2 += w4.z * h4.z; p3 += w4.w * h4.w;
    }
    #pragma unroll
    for (int m = 0; m < 8; ++m) {
      float4 h4 = ((const float4*)h1)[m]; float4 w4 = wpreg[8 + m];
      p0 += w4.x * h4.x; p1 += w4.y * h4.y;
      p2 += w4.z * h4.z; p3 += w4.w * h4.w;
    }
    float pr = (p0 + p1) + (p2 + p3);
    pr += __shfl_xor(pr, 1);
    pr += __shfl_xor(pr, 2);
    pr += __shfl_xor(pr, 4);
    if (s == 0) params[(size_t)(BB - 1) * PDIM + pcol] = pr + bp;
  }
}

// samples[b,o] = sum_i w_i * (mu_i + (var_i+1e-6)*eps[i,b,o])
__global__ void mix_kernel(const float* __restrict__ params,
                           const float* __restrict__ eps,
                           float* __restrict__ out)
{
  int b = blockIdx.x, o = threadIdx.x;
  const float* pr = params + (size_t)b * PDIM;
  float s = 0.f;
  #pragma unroll
  for (int i = 0; i < G5; ++i) {
    float mu  = pr[i * ODIM + o];
    float var = pr[2 * i * ODIM + o] + 1e-6f;
    float w   = pr[2 * G5 * ODIM + i];
    float e   = eps[((size_t)i * BB + b) * ODIM + o];
    s += w * (mu + var * e);
  }
  out[(size_t)b * ODIM + o] = s;
}

extern "C" void kernel_launch(void* const* d_in, const int* in_sizes, int n_in,
                              void* d_out, int out_size, void* d_ws, size_t ws_size,
                              hipStream_t stream) {
  const float* ys     = (const float*)d_in[0];
  const float* W_ih   = (const float*)d_in[1];
  const float* W_hh   = (const float*)d_in[2];
  const float* b_ih   = (const float*)d_in[3];
  const float* b_hh   = (const float*)d_in[4];
  const float* W_proj = (const float*)d_in[5];
  const float* b_proj = (const float*)d_in[6];
  const float* eps    = (const float*)d_in[7];
  float* out = (float*)d_out;

  // workspace layout
  char* ws = (char*)d_ws;
  unsigned long long* hOut = (unsigned long long*)ws;       // 2*512*8 = 8 KB
  float* xp_loc = (float*)(ws + 2 * HDIM * 8);              // 16*512*96*4 = 3 MB
  float* params = xp_loc + (size_t)NB * BB * ROWS;          // 512*1285*4

  hipMemsetAsync(hOut, 0xFF, 2 * HDIM * 8, stream);         // tags invalid

  gru_kernel<<<NB, TPB, 0, stream>>>(ys, W_ih, W_hh, b_ih, b_hh,
                                     W_proj, b_proj, hOut, xp_loc, params);

  mix_kernel<<<BB, ODIM, 0, stream>>>(params, eps, out);
}